// Round 6
// baseline (308.125 us; speedup 1.0000x reference)
//
#include <hip/hip_runtime.h>
#include <hip/hip_bf16.h>
#include <stdint.h>

// B=2, T=4096, D=1024, H=16, HS=64. Pipeline:
// cvt -> GEMM qkv (bf16 MFMA) -> flash attn (Q-tile 128: 2 indep Q-frags/wave,
// swapped QK^T lane-local softmax, bpermute P redistribution, defer-rescale,
// dbuf swizzled K/V, setprio) -> GEMM out.

typedef __bf16 bf16x8 __attribute__((ext_vector_type(8)));
typedef float f32x4 __attribute__((ext_vector_type(4)));
typedef __attribute__((address_space(1))) void gvoid_t;
typedef __attribute__((address_space(3))) void lvoid_t;

using hbf = __hip_bfloat16;

#define QSCALE (0.125f * 1.44269504088896f)  // 1/sqrt(HS) * log2(e)

static __device__ __forceinline__ void gload_lds16(const void* g, void* l) {
  __builtin_amdgcn_global_load_lds((gvoid_t*)g, (lvoid_t*)l, 16, 0, 0);
}

static __device__ __forceinline__ uint16_t b2u(float x) {
  hbf h = __float2bfloat16(x);
  return *reinterpret_cast<uint16_t*>(&h);
}

// ---------------- converters ----------------

__global__ void k_cvt_x(const float* __restrict__ x, hbf* __restrict__ xb) {
  int i = (blockIdx.x * 256 + threadIdx.x) * 4;
  float4 v = *reinterpret_cast<const float4*>(x + i);
  hbf h[4] = {__float2bfloat16(v.x), __float2bfloat16(v.y),
              __float2bfloat16(v.z), __float2bfloat16(v.w)};
  *reinterpret_cast<ushort4*>(xb + i) = *reinterpret_cast<ushort4*>(h);
}

__global__ void k_cvt_w(const float* __restrict__ Wq, const float* __restrict__ Wk,
                        const float* __restrict__ Wv, hbf* __restrict__ Wt) {
  int idx = blockIdx.x * 256 + threadIdx.x;   // 3072*1024
  int d = idx & 1023, r = idx >> 10;
  int m = r >> 10, rem = r & 1023;
  int h = rem >> 6, e = rem & 63;
  const float* W = (m == 0) ? Wq : (m == 1) ? Wk : Wv;
  float v = W[(h << 10 | d) * 64 + e];
  if (m == 0) v *= QSCALE;
  Wt[idx] = __float2bfloat16(v);
}

__global__ void k_cvt_bias(const float* __restrict__ bq, const float* __restrict__ bk,
                           const float* __restrict__ bv, float* __restrict__ biasc) {
  int r = blockIdx.x * 256 + threadIdx.x;     // 0..3071
  int m = r >> 10, rem = r & 1023;
  const float* bsrc = (m == 0) ? bq : (m == 1) ? bk : bv;
  float v = bsrc[rem];
  if (m == 0) v *= QSCALE;
  biasc[r] = v;
}

__global__ void k_cvt_wp(const float* __restrict__ Wp, hbf* __restrict__ Wpt) {
  int idx = blockIdx.x * 256 + threadIdx.x;   // 1024*1024
  int o = idx >> 10, d = idx & 1023;
  Wpt[idx] = __float2bfloat16(Wp[(d << 10) + o]);
}

// ---------------- QKV projection GEMM ----------------

__global__ __launch_bounds__(256) void k_gemm_qkv(
    const hbf* __restrict__ A, const hbf* __restrict__ Bw,
    const float* __restrict__ biasc, hbf* __restrict__ qkv) {
  __shared__ __align__(16) hbf sA[128 * 64];
  __shared__ __align__(16) hbf sB[128 * 64];
  const int tid = threadIdx.x;
  const int lane = tid & 63, wid = tid >> 6;
  const int m0 = blockIdx.x * 128, n0 = blockIdx.y * 128;
  const int g = lane >> 4, cl = lane & 15;

  const f32x4 fz = {0.f, 0.f, 0.f, 0.f};
  f32x4 acc[4][4];
#pragma unroll
  for (int a = 0; a < 4; ++a)
#pragma unroll
    for (int b = 0; b < 4; ++b) acc[a][b] = fz;

  const int srow = wid * 32 + (lane >> 3);
  const int scol = (lane & 7) * 8;

  for (int kt = 0; kt < 16; ++kt) {
    const int k0 = kt * 64;
#pragma unroll
    for (int t = 0; t < 4; ++t) {
      const int r = srow + t * 8;
      gload_lds16(A + (size_t)(m0 + r) * 1024 + k0 + scol, sA + (wid * 32 + t * 8) * 64);
      gload_lds16(Bw + (size_t)(n0 + r) * 1024 + k0 + scol, sB + (wid * 32 + t * 8) * 64);
    }
    __syncthreads();
#pragma unroll
    for (int ks = 0; ks < 2; ++ks) {
      const int ko = ks * 32 + g * 8;
      bf16x8 af[4], bfr[4];
#pragma unroll
      for (int rt = 0; rt < 4; ++rt)
        af[rt] = *reinterpret_cast<const bf16x8*>(sA + ((wid & 1) * 64 + rt * 16 + cl) * 64 + ko);
#pragma unroll
      for (int ct = 0; ct < 4; ++ct)
        bfr[ct] = *reinterpret_cast<const bf16x8*>(sB + ((wid >> 1) * 64 + ct * 16 + cl) * 64 + ko);
#pragma unroll
      for (int rt = 0; rt < 4; ++rt)
#pragma unroll
        for (int ct = 0; ct < 4; ++ct)
          acc[rt][ct] = __builtin_amdgcn_mfma_f32_16x16x32_bf16(af[rt], bfr[ct], acc[rt][ct], 0, 0, 0);
    }
    __syncthreads();
  }

#pragma unroll
  for (int rt = 0; rt < 4; ++rt)
#pragma unroll
    for (int ct = 0; ct < 4; ++ct) {
      const int colg = n0 + (wid >> 1) * 64 + ct * 16 + cl;
      const int mi = colg >> 10, rem = colg & 1023;
      const int h = rem >> 6, e = rem & 63;
      const float bi = biasc[colg];
#pragma unroll
      for (int i = 0; i < 4; ++i) {
        const int rowg = m0 + (wid & 1) * 64 + rt * 16 + g * 4 + i;
        const int b = rowg >> 12, t = rowg & 4095;
        qkv[(((size_t)mi * 32 + b * 16 + h) * 4096 + t) * 64 + e] =
            __float2bfloat16(acc[rt][ct][i] + bi);
      }
    }
}

// ---------------- flash attention ----------------
// grid (bh=32, 32); qtb = 31 - blockIdx.y. Q-tile 128: 4 waves x 32 q-rows
// (2 Q-frags each), KV tiles of 64 -> tiles jt = 0..2*qtb+1.
// Swapped QK^T: accS[h] = mfma(K, Q[h]) is S^T; lane (g,cl) owns q-row
// (wid*32+h*16+cl) with kv = nt*16+g*4+i -> row stats via in-reg tree +
// shfl_xor(16,32). Defer-rescale (THR=8, exp2 domain). P -> bf16 pack ->
// ds_bpermute into PV B-frag; PV = mfma(V^T, P^T). K: XOR-swizzled via
// global_load_lds; V: transposed+swizzled, T14 reg-staged. Last tile:
// waves 0,1 fully masked -> wave-uniform skip.

__global__ __launch_bounds__(256) void k_flash(
    const hbf* __restrict__ qkv, hbf* __restrict__ attn) {
  __shared__ __align__(16) __bf16 sK[2][64 * 64];
  __shared__ __align__(16) __bf16 sV[2][64 * 64];
  const int tid = threadIdx.x, lane = tid & 63, wid = tid >> 6;
  const int g = lane >> 4, cl = lane & 15;
  const int bh = blockIdx.x;
  const int qtb = (int)gridDim.y - 1 - (int)blockIdx.y;  // 0..31
  const int q0 = qtb * 128;
  const int ntile = 2 * qtb + 2;
  const hbf* Q  = qkv + (size_t)bh * (4096 * 64);
  const hbf* Kp = qkv + (size_t)(32 + bh) * (4096 * 64);
  const hbf* Vp = qkv + (size_t)(64 + bh) * (4096 * 64);
  const float NEG_INF = -__builtin_inff();

  const int koff = (wid * 16 + (lane >> 3)) * 64 + (((lane & 7) ^ (lane >> 3)) * 8);
  const int vr = tid >> 2, vc0 = (tid & 3) * 16;
  const int vgoff = vr * 64 + vc0;

  bf16x8 aq[2][2];  // [q-half][ks]
#pragma unroll
  for (int h = 0; h < 2; ++h)
#pragma unroll
    for (int ks = 0; ks < 2; ++ks)
      aq[h][ks] = *reinterpret_cast<const bf16x8*>(
          Q + (size_t)(q0 + wid * 32 + h * 16 + cl) * 64 + ks * 32 + g * 8);

  const f32x4 fz = {0.f, 0.f, 0.f, 0.f};
  f32x4 accO[2][4];
#pragma unroll
  for (int h = 0; h < 2; ++h)
#pragma unroll
    for (int nt = 0; nt < 4; ++nt) accO[h][nt] = fz;
  float mrow[2] = {NEG_INF, NEG_INF}, lrow[2] = {0.f, 0.f};

  auto vwrite = [&](__bf16* dst, bf16x8 a, bf16x8 b) {
#pragma unroll
    for (int u = 0; u < 8; ++u) {
      const int e = vc0 + u;
      dst[e * 64 + (((vr >> 3) ^ (e & 7) ^ ((e >> 3) & 7)) * 8) + (vr & 7)] = a[u];
    }
#pragma unroll
    for (int u = 8; u < 16; ++u) {
      const int e = vc0 + u;
      dst[e * 64 + (((vr >> 3) ^ (e & 7) ^ ((e >> 3) & 7)) * 8) + (vr & 7)] = b[u - 8];
    }
  };

  // prologue: stage tile 0 into buf 0
  gload_lds16(Kp + koff,       &sK[0][wid * 1024]);
  gload_lds16(Kp + koff + 512, &sK[0][wid * 1024 + 512]);
  {
    bf16x8 a = *reinterpret_cast<const bf16x8*>(Vp + vgoff);
    bf16x8 b = *reinterpret_cast<const bf16x8*>(Vp + vgoff + 8);
    vwrite(sV[0], a, b);
  }
  __syncthreads();

  const int aA = (((g & 1) * 32) + cl) << 2;  // bpermute byte addr
  const int aB = aA + 64;
  const bool ghi = (g & 2) != 0;

  int buf = 0;
  for (int jt = 0; jt < ntile; ++jt) {
    bf16x8 va, vb;
    if (jt < ntile - 1) {  // prefetch next tile: K -> LDS DMA, V -> regs
      const hbf* Kg = Kp + (size_t)(jt + 1) * 4096;
      gload_lds16(Kg + koff,       &sK[buf ^ 1][wid * 1024]);
      gload_lds16(Kg + koff + 512, &sK[buf ^ 1][wid * 1024 + 512]);
      const hbf* Vg = Vp + (size_t)(jt + 1) * 4096 + vgoff;
      va = *reinterpret_cast<const bf16x8*>(Vg);
      vb = *reinterpret_cast<const bf16x8*>(Vg + 8);
    }

    // last tile: waves 0,1 (q-rows 0..63 of block) are fully masked
    const bool active = !((jt == ntile - 1) && (wid < 2));
    if (active) {
      // S^T = K Q^T for both q-halves (K-frag read once, used twice)
      const __bf16* sKb = sK[buf];
      f32x4 accS[2][4];
      __builtin_amdgcn_s_setprio(1);
#pragma unroll
      for (int nt = 0; nt < 4; ++nt) {
        f32x4 s0 = fz, s1 = fz;
#pragma unroll
        for (int ks = 0; ks < 2; ++ks) {
          bf16x8 bk = *reinterpret_cast<const bf16x8*>(
              sKb + (nt * 16 + cl) * 64 + (((ks * 4 + g) ^ (cl & 7)) * 8));
          s0 = __builtin_amdgcn_mfma_f32_16x16x32_bf16(bk, aq[0][ks], s0, 0, 0, 0);
          s1 = __builtin_amdgcn_mfma_f32_16x16x32_bf16(bk, aq[1][ks], s1, 0, 0, 0);
        }
        accS[0][nt] = s0;
        accS[1][nt] = s1;
      }
      __builtin_amdgcn_s_setprio(0);

      if (jt >= 2 * qtb) {  // diagonal region: mask kv > q (relative)
        const int sh = (jt - 2 * qtb) * 64;
#pragma unroll
        for (int h = 0; h < 2; ++h) {
          const int ql = wid * 32 + h * 16 + cl - sh;
#pragma unroll
          for (int nt = 0; nt < 4; ++nt)
#pragma unroll
            for (int i = 0; i < 4; ++i)
              if (nt * 16 + g * 4 + i > ql) accS[h][nt][i] = NEG_INF;
        }
      }

      uint32_t pk[2][4][2];
#pragma unroll
      for (int h = 0; h < 2; ++h) {
        // row stats: in-reg tree + cross-g reduce (lanes cl+16k share a row)
        float m0 = fmaxf(fmaxf(accS[h][0][0], accS[h][0][1]), fmaxf(accS[h][0][2], accS[h][0][3]));
        float m1 = fmaxf(fmaxf(accS[h][1][0], accS[h][1][1]), fmaxf(accS[h][1][2], accS[h][1][3]));
        float m2 = fmaxf(fmaxf(accS[h][2][0], accS[h][2][1]), fmaxf(accS[h][2][2], accS[h][2][3]));
        float m3 = fmaxf(fmaxf(accS[h][3][0], accS[h][3][1]), fmaxf(accS[h][3][2], accS[h][3][3]));
        float pmax = fmaxf(fmaxf(m0, m1), fmaxf(m2, m3));
        pmax = fmaxf(pmax, __shfl_xor(pmax, 16));
        pmax = fmaxf(pmax, __shfl_xor(pmax, 32));

        if (!__all(pmax - mrow[h] <= 8.f)) {  // defer-rescale (T13)
          const float mn = fmaxf(mrow[h], pmax);
          const float corr = __builtin_amdgcn_exp2f(mrow[h] - mn);
          mrow[h] = mn;
          lrow[h] *= corr;
#pragma unroll
          for (int nt = 0; nt < 4; ++nt)
#pragma unroll
            for (int i = 0; i < 4; ++i) accO[h][nt][i] *= corr;
        }

        float p[16];
#pragma unroll
        for (int nt = 0; nt < 4; ++nt)
#pragma unroll
          for (int i = 0; i < 4; ++i)
            p[nt * 4 + i] = __builtin_amdgcn_exp2f(accS[h][nt][i] - mrow[h]);
        const float s0 = (p[0] + p[1]) + (p[2] + p[3]);
        const float s1 = (p[4] + p[5]) + (p[6] + p[7]);
        const float s2 = (p[8] + p[9]) + (p[10] + p[11]);
        const float s3 = (p[12] + p[13]) + (p[14] + p[15]);
        float rs = (s0 + s1) + (s2 + s3);
        rs += __shfl_xor(rs, 16);
        rs += __shfl_xor(rs, 32);
        lrow[h] += rs;

#pragma unroll
        for (int nt = 0; nt < 4; ++nt)
#pragma unroll
          for (int d = 0; d < 2; ++d)
            pk[h][nt][d] = (uint32_t)b2u(p[nt * 4 + 2 * d]) |
                           ((uint32_t)b2u(p[nt * 4 + 2 * d + 1]) << 16);
      }

      // PV^T for both halves; V-frag read once, used twice
      const __bf16* sVb = sV[buf];
#pragma unroll
      for (int ks = 0; ks < 2; ++ks) {
        const int n0i = ks * 2, n1i = n0i + 1;
        union { uint32_t u[4]; bf16x8 v; } bP[2];
#pragma unroll
        for (int h = 0; h < 2; ++h) {
          const int t0 = __builtin_amdgcn_ds_bpermute(aA, (int)pk[h][n0i][0]);
          const int t1 = __builtin_amdgcn_ds_bpermute(aA, (int)pk[h][n1i][0]);
          bP[h].u[0] = (uint32_t)(ghi ? t1 : t0);
          const int t2 = __builtin_amdgcn_ds_bpermute(aA, (int)pk[h][n0i][1]);
          const int t3 = __builtin_amdgcn_ds_bpermute(aA, (int)pk[h][n1i][1]);
          bP[h].u[1] = (uint32_t)(ghi ? t3 : t2);
          const int t4 = __builtin_amdgcn_ds_bpermute(aB, (int)pk[h][n0i][0]);
          const int t5 = __builtin_amdgcn_ds_bpermute(aB, (int)pk[h][n1i][0]);
          bP[h].u[2] = (uint32_t)(ghi ? t5 : t4);
          const int t6 = __builtin_amdgcn_ds_bpermute(aB, (int)pk[h][n0i][1]);
          const int t7 = __builtin_amdgcn_ds_bpermute(aB, (int)pk[h][n1i][1]);
          bP[h].u[3] = (uint32_t)(ghi ? t7 : t6);
        }
        __builtin_amdgcn_s_setprio(1);
#pragma unroll
        for (int nt = 0; nt < 4; ++nt) {
          const int e = nt * 16 + cl;
          const int chunk = (ks * 4 + g) ^ (cl & 7) ^ ((2 * nt + (cl >> 3)) & 7);
          bf16x8 bv = *reinterpret_cast<const bf16x8*>(sVb + e * 64 + chunk * 8);
          accO[0][nt] = __builtin_amdgcn_mfma_f32_16x16x32_bf16(bv, bP[0].v, accO[0][nt], 0, 0, 0);
          accO[1][nt] = __builtin_amdgcn_mfma_f32_16x16x32_bf16(bv, bP[1].v, accO[1][nt], 0, 0, 0);
        }
        __builtin_amdgcn_s_setprio(0);
      }
    }

    if (jt < ntile - 1) vwrite(sV[buf ^ 1], va, vb);
    __syncthreads();  // drains K DMA + V writes; all waves done with buf
    buf ^= 1;
  }

  // epilogue: accO^T holds [e = nt*16+g*4+i][q]; 8B packed stores per half
#pragma unroll
  for (int h = 0; h < 2; ++h) {
    const float inv = 1.0f / lrow[h];
    const int qrow = q0 + wid * 32 + h * 16 + cl;
    hbf* arow = attn + ((size_t)(bh >> 4) * 4096 + qrow) * 1024 + (bh & 15) * 64;
#pragma unroll
    for (int nt = 0; nt < 4; ++nt) {
      ushort4 o;
      o.x = b2u(accO[h][nt][0] * inv);
      o.y = b2u(accO[h][nt][1] * inv);
      o.z = b2u(accO[h][nt][2] * inv);
      o.w = b2u(accO[h][nt][3] * inv);
      *reinterpret_cast<ushort4*>(arow + nt * 16 + g * 4) = o;
    }
  }
}

// ---------------- output projection GEMM ----------------

__global__ __launch_bounds__(256) void k_gemm_out(
    const hbf* __restrict__ A, const hbf* __restrict__ Bw,
    const float* __restrict__ bp, float* __restrict__ out) {
  __shared__ __align__(16) hbf sA[128 * 64];
  __shared__ __align__(16) hbf sB[128 * 64];
  const int tid = threadIdx.x;
  const int lane = tid & 63, wid = tid >> 6;
  const int m0 = blockIdx.x * 128, n0 = blockIdx.y * 128;
  const int g = lane >> 4, cl = lane & 15;

  const f32x4 fz = {0.f, 0.f, 0.f, 0.f};
  f32x4 acc[4][4];
#pragma unroll
  for (int a = 0; a < 4; ++a)
#pragma unroll
    for (int b = 0; b < 4; ++b) acc[a][b] = fz;

  const int srow = wid * 32 + (lane >> 3);
  const int scol = (lane & 7) * 8;

  for (int kt = 0; kt < 16; ++kt) {
    const int k0 = kt * 64;
#pragma unroll
    for (int t = 0; t < 4; ++t) {
      const int r = srow + t * 8;
      gload_lds16(A + (size_t)(m0 + r) * 1024 + k0 + scol, sA + (wid * 32 + t * 8) * 64);
      gload_lds16(Bw + (size_t)(n0 + r) * 1024 + k0 + scol, sB + (wid * 32 + t * 8) * 64);
    }
    __syncthreads();
#pragma unroll
    for (int ks = 0; ks < 2; ++ks) {
      const int ko = ks * 32 + g * 8;
      bf16x8 af[4], bfr[4];
#pragma unroll
      for (int rt = 0; rt < 4; ++rt)
        af[rt] = *reinterpret_cast<const bf16x8*>(sA + ((wid & 1) * 64 + rt * 16 + cl) * 64 + ko);
#pragma unroll
      for (int ct = 0; ct < 4; ++ct)
        bfr[ct] = *reinterpret_cast<const bf16x8*>(sB + ((wid >> 1) * 64 + ct * 16 + cl) * 64 + ko);
#pragma unroll
      for (int rt = 0; rt < 4; ++rt)
#pragma unroll
        for (int ct = 0; ct < 4; ++ct)
          acc[rt][ct] = __builtin_amdgcn_mfma_f32_16x16x32_bf16(af[rt], bfr[ct], acc[rt][ct], 0, 0, 0);
    }
    __syncthreads();
  }

#pragma unroll
  for (int rt = 0; rt < 4; ++rt)
#pragma unroll
    for (int ct = 0; ct < 4; ++ct) {
      const int colg = n0 + (wid >> 1) * 64 + ct * 16 + cl;
      const float bi = bp[colg];
#pragma unroll
      for (int i = 0; i < 4; ++i) {
        const int rowg = m0 + (wid & 1) * 64 + rt * 16 + g * 4 + i;
        out[(size_t)rowg * 1024 + colg] = acc[rt][ct][i] + bi;
      }
    }
}

// ---------------- launcher ----------------

extern "C" void kernel_launch(void* const* d_in, const int* in_sizes, int n_in,
                              void* d_out, int out_size, void* d_ws, size_t ws_size,
                              hipStream_t stream) {
  const float* x  = (const float*)d_in[0];
  const float* Wq = (const float*)d_in[1];
  const float* Wk = (const float*)d_in[2];
  const float* Wv = (const float*)d_in[3];
  const float* bq = (const float*)d_in[4];
  const float* bk = (const float*)d_in[5];
  const float* bv = (const float*)d_in[6];
  const float* Wp = (const float*)d_in[7];
  const float* bp = (const float*)d_in[8];
  float* out = (float*)d_out;

  char* ws = (char*)d_ws;
  hbf*   xb    = (hbf*)ws;                                   // 16 MiB (reused as attn_out)
  hbf*   Wt    = (hbf*)(ws + 16777216);                      // 6 MiB
  hbf*   Wpt   = (hbf*)(ws + 16777216 + 6291456);            // 2 MiB
  float* biasc = (float*)(ws + 16777216 + 6291456 + 2097152);// 12 KiB (+pad)
  hbf*   qkv   = (hbf*)(ws + 16777216 + 6291456 + 2097152 + 16384); // 48 MiB
  hbf*   attn  = xb;

  k_cvt_x   <<<8192,  256, 0, stream>>>(x, xb);
  k_cvt_w   <<<12288, 256, 0, stream>>>(Wq, Wk, Wv, Wt);
  k_cvt_bias<<<12,    256, 0, stream>>>(bq, bk, bv, biasc);
  k_cvt_wp  <<<4096,  256, 0, stream>>>(Wp, Wpt);

  dim3 g1(64, 24); k_gemm_qkv<<<g1, 256, 0, stream>>>(xb, Wt, biasc, qkv);
  dim3 g2(32, 32); k_flash   <<<g2, 256, 0, stream>>>(qkv, attn);
  dim3 g3(64, 8);  k_gemm_out<<<g3, 256, 0, stream>>>(attn, Wpt, bp, out);
}

// Round 7
// 303.287 us; speedup vs baseline: 1.0160x; 1.0160x over previous
//
#include <hip/hip_runtime.h>
#include <hip/hip_bf16.h>
#include <stdint.h>

// B=2, T=4096, D=1024, H=16, HS=64. Pipeline:
// cvt -> GEMM qkv (bf16 MFMA; V written TRANSPOSED [bh][e][t]) -> flash attn
// (swapped QK^T lane-local softmax, bpermute P redistribution, defer-rescale,
// dbuf K/V both via swizzled global_load_lds, setprio) -> GEMM out.

typedef __bf16 bf16x8 __attribute__((ext_vector_type(8)));
typedef float f32x4 __attribute__((ext_vector_type(4)));
typedef __attribute__((address_space(1))) void gvoid_t;
typedef __attribute__((address_space(3))) void lvoid_t;

using hbf = __hip_bfloat16;

#define QSCALE (0.125f * 1.44269504088896f)  // 1/sqrt(HS) * log2(e)

static __device__ __forceinline__ void gload_lds16(const void* g, void* l) {
  __builtin_amdgcn_global_load_lds((gvoid_t*)g, (lvoid_t*)l, 16, 0, 0);
}

static __device__ __forceinline__ uint16_t b2u(float x) {
  hbf h = __float2bfloat16(x);
  return *reinterpret_cast<uint16_t*>(&h);
}

// ---------------- converters ----------------

__global__ void k_cvt_x(const float* __restrict__ x, hbf* __restrict__ xb) {
  int i = (blockIdx.x * 256 + threadIdx.x) * 4;
  float4 v = *reinterpret_cast<const float4*>(x + i);
  hbf h[4] = {__float2bfloat16(v.x), __float2bfloat16(v.y),
              __float2bfloat16(v.z), __float2bfloat16(v.w)};
  *reinterpret_cast<ushort4*>(xb + i) = *reinterpret_cast<ushort4*>(h);
}

__global__ void k_cvt_w(const float* __restrict__ Wq, const float* __restrict__ Wk,
                        const float* __restrict__ Wv, hbf* __restrict__ Wt) {
  int idx = blockIdx.x * 256 + threadIdx.x;   // 3072*1024
  int d = idx & 1023, r = idx >> 10;
  int m = r >> 10, rem = r & 1023;
  int h = rem >> 6, e = rem & 63;
  const float* W = (m == 0) ? Wq : (m == 1) ? Wk : Wv;
  float v = W[(h << 10 | d) * 64 + e];
  if (m == 0) v *= QSCALE;
  Wt[idx] = __float2bfloat16(v);
}

__global__ void k_cvt_bias(const float* __restrict__ bq, const float* __restrict__ bk,
                           const float* __restrict__ bv, float* __restrict__ biasc) {
  int r = blockIdx.x * 256 + threadIdx.x;     // 0..3071
  int m = r >> 10, rem = r & 1023;
  const float* bsrc = (m == 0) ? bq : (m == 1) ? bk : bv;
  float v = bsrc[rem];
  if (m == 0) v *= QSCALE;
  biasc[r] = v;
}

__global__ void k_cvt_wp(const float* __restrict__ Wp, hbf* __restrict__ Wpt) {
  int idx = blockIdx.x * 256 + threadIdx.x;   // 1024*1024
  int o = idx >> 10, d = idx & 1023;
  Wpt[idx] = __float2bfloat16(Wp[(d << 10) + o]);
}

// ---------------- QKV projection GEMM ----------------
// Q,K -> qkv[mi][bh][t][e] ; V -> transposed [bh][e][t] at the mi=2 section.

__global__ __launch_bounds__(256) void k_gemm_qkv(
    const hbf* __restrict__ A, const hbf* __restrict__ Bw,
    const float* __restrict__ biasc, hbf* __restrict__ qkv) {
  __shared__ __align__(16) hbf sA[128 * 64];
  __shared__ __align__(16) hbf sB[128 * 64];
  const int tid = threadIdx.x;
  const int lane = tid & 63, wid = tid >> 6;
  const int m0 = blockIdx.x * 128, n0 = blockIdx.y * 128;
  const int g = lane >> 4, cl = lane & 15;

  const f32x4 fz = {0.f, 0.f, 0.f, 0.f};
  f32x4 acc[4][4];
#pragma unroll
  for (int a = 0; a < 4; ++a)
#pragma unroll
    for (int b = 0; b < 4; ++b) acc[a][b] = fz;

  const int srow = wid * 32 + (lane >> 3);
  const int scol = (lane & 7) * 8;

  for (int kt = 0; kt < 16; ++kt) {
    const int k0 = kt * 64;
#pragma unroll
    for (int t = 0; t < 4; ++t) {
      const int r = srow + t * 8;
      gload_lds16(A + (size_t)(m0 + r) * 1024 + k0 + scol, sA + (wid * 32 + t * 8) * 64);
      gload_lds16(Bw + (size_t)(n0 + r) * 1024 + k0 + scol, sB + (wid * 32 + t * 8) * 64);
    }
    __syncthreads();
#pragma unroll
    for (int ks = 0; ks < 2; ++ks) {
      const int ko = ks * 32 + g * 8;
      bf16x8 af[4], bfr[4];
#pragma unroll
      for (int rt = 0; rt < 4; ++rt)
        af[rt] = *reinterpret_cast<const bf16x8*>(sA + ((wid & 1) * 64 + rt * 16 + cl) * 64 + ko);
#pragma unroll
      for (int ct = 0; ct < 4; ++ct)
        bfr[ct] = *reinterpret_cast<const bf16x8*>(sB + ((wid >> 1) * 64 + ct * 16 + cl) * 64 + ko);
#pragma unroll
      for (int rt = 0; rt < 4; ++rt)
#pragma unroll
        for (int ct = 0; ct < 4; ++ct)
          acc[rt][ct] = __builtin_amdgcn_mfma_f32_16x16x32_bf16(af[rt], bfr[ct], acc[rt][ct], 0, 0, 0);
    }
    __syncthreads();
  }

#pragma unroll
  for (int rt = 0; rt < 4; ++rt)
#pragma unroll
    for (int ct = 0; ct < 4; ++ct) {
      const int colg = n0 + (wid >> 1) * 64 + ct * 16 + cl;
      const int mi = colg >> 10, rem = colg & 1023;
      const int h = rem >> 6, e = rem & 63;
      const float bi = biasc[colg];
#pragma unroll
      for (int i = 0; i < 4; ++i) {
        const int rowg = m0 + (wid & 1) * 64 + rt * 16 + g * 4 + i;
        const int b = rowg >> 12, t = rowg & 4095;
        const hbf val = __float2bfloat16(acc[rt][ct][i] + bi);
        if (mi == 2) {
          // V transposed: section base 2*32*262144, then [bh][e][t]
          qkv[(size_t)64 * 262144 + (size_t)(b * 16 + h) * 262144 + (size_t)e * 4096 + t] = val;
        } else {
          qkv[(((size_t)mi * 32 + b * 16 + h) * 4096 + t) * 64 + e] = val;
        }
      }
    }
}

// ---------------- flash attention ----------------
// grid (bh=32, 64); qt = 63 - blockIdx.y. 4 waves x 16 q-rows, KV tiles of 64.
// Swapped QK^T: accS = mfma(K, Q) holds S^T; lane (g,cl) owns q-row cl with
// kv = nt*16+g*4+i -> row stats via in-reg tree + shfl_xor(16,32).
// Defer-rescale (THR=8, exp2). P -> bf16 pack -> ds_bpermute into PV B-frag;
// PV = mfma(V^T, P^T). K AND V^T staged via XOR-swizzled global_load_lds
// (V pre-transposed by GEMM1). Double-buffered, one barrier/iter. setprio
// around MFMA clusters.

__global__ __launch_bounds__(256) void k_flash(
    const hbf* __restrict__ qkv, hbf* __restrict__ attn) {
  __shared__ __align__(16) __bf16 sK[2][64 * 64];
  __shared__ __align__(16) __bf16 sV[2][64 * 64];
  const int tid = threadIdx.x, lane = tid & 63, wid = tid >> 6;
  const int g = lane >> 4, cl = lane & 15;
  const int bh = blockIdx.x;
  const int qt = (int)gridDim.y - 1 - (int)blockIdx.y;
  const int q0 = qt * 64;
  const hbf* Q  = qkv + (size_t)bh * 262144;
  const hbf* Kp = qkv + (size_t)(32 + bh) * 262144;
  const hbf* Vp = qkv + (size_t)(64 + bh) * 262144;  // [e=64][t=4096]
  const float NEG_INF = -__builtin_inff();

  // K: row r = wid*16+(lane>>3), src chunk pre-swizzled (both-sides rule).
  const int koff = (wid * 16 + (lane >> 3)) * 64 + (((lane & 7) ^ (lane >> 3)) * 8);
  // V^T: e-row = wid*16+(lane>>3) (stride 4096), same chunk swizzle on t.
  const int voff = (wid * 16 + (lane >> 3)) * 4096 + (((lane & 7) ^ (lane >> 3)) * 8);

  bf16x8 aq[2];
#pragma unroll
  for (int ks = 0; ks < 2; ++ks)
    aq[ks] = *reinterpret_cast<const bf16x8*>(Q + (size_t)(q0 + wid * 16 + cl) * 64 + ks * 32 + g * 8);

  const f32x4 fz = {0.f, 0.f, 0.f, 0.f};
  f32x4 accO[4];
#pragma unroll
  for (int nt = 0; nt < 4; ++nt) accO[nt] = fz;
  float mrow = NEG_INF, lrow = 0.f;   // per-lane copy of row (cl) stats

  // prologue: stage tile 0 into buf 0 (K rows + V^T e-rows)
  gload_lds16(Kp + koff,         &sK[0][wid * 1024]);
  gload_lds16(Kp + koff + 512,   &sK[0][wid * 1024 + 512]);
  gload_lds16(Vp + voff,         &sV[0][wid * 1024]);
  gload_lds16(Vp + voff + 32768, &sV[0][wid * 1024 + 512]);
  __syncthreads();

  const int aA = (((g & 1) * 32) + cl) << 2;  // bpermute byte addr
  const int aB = aA + 64;                     // +16 lanes
  const bool ghi = (g & 2) != 0;

  int buf = 0;
  for (int j = 0; j <= qt; ++j) {
    if (j < qt) {  // prefetch tile j+1 into other buffer (pure DMA)
      const hbf* Kg = Kp + (size_t)(j + 1) * 4096;
      gload_lds16(Kg + koff,       &sK[buf ^ 1][wid * 1024]);
      gload_lds16(Kg + koff + 512, &sK[buf ^ 1][wid * 1024 + 512]);
      const hbf* Vg = Vp + (j + 1) * 64;
      gload_lds16(Vg + voff,         &sV[buf ^ 1][wid * 1024]);
      gload_lds16(Vg + voff + 32768, &sV[buf ^ 1][wid * 1024 + 512]);
    }

    // S^T = K Q^T : lane holds q-row cl, kv = nt*16 + g*4 + i
    const __bf16* sKb = sK[buf];
    f32x4 accS[4];
    __builtin_amdgcn_s_setprio(1);
#pragma unroll
    for (int nt = 0; nt < 4; ++nt) {
      f32x4 s = fz;
#pragma unroll
      for (int ks = 0; ks < 2; ++ks) {
        bf16x8 bk = *reinterpret_cast<const bf16x8*>(
            sKb + (nt * 16 + cl) * 64 + (((ks * 4 + g) ^ (cl & 7)) * 8));
        s = __builtin_amdgcn_mfma_f32_16x16x32_bf16(bk, aq[ks], s, 0, 0, 0);
      }
      accS[nt] = s;
    }
    __builtin_amdgcn_s_setprio(0);
    if (j == qt) {  // causal: mask kv > q_l (q_l = wid*16+cl)
      const int ql = wid * 16 + cl;
#pragma unroll
      for (int nt = 0; nt < 4; ++nt)
#pragma unroll
        for (int i = 0; i < 4; ++i)
          if (nt * 16 + g * 4 + i > ql) accS[nt][i] = NEG_INF;
    }

    // row stats: in-reg tree over own 16 + cross-g reduce (lanes cl+16k share row cl)
    float m0 = fmaxf(fmaxf(accS[0][0], accS[0][1]), fmaxf(accS[0][2], accS[0][3]));
    float m1 = fmaxf(fmaxf(accS[1][0], accS[1][1]), fmaxf(accS[1][2], accS[1][3]));
    float m2 = fmaxf(fmaxf(accS[2][0], accS[2][1]), fmaxf(accS[2][2], accS[2][3]));
    float m3 = fmaxf(fmaxf(accS[3][0], accS[3][1]), fmaxf(accS[3][2], accS[3][3]));
    float pmax = fmaxf(fmaxf(m0, m1), fmaxf(m2, m3));
    pmax = fmaxf(pmax, __shfl_xor(pmax, 16));
    pmax = fmaxf(pmax, __shfl_xor(pmax, 32));

    if (!__all(pmax - mrow <= 8.f)) {  // defer-rescale (T13)
      const float mn = fmaxf(mrow, pmax);
      const float corr = __builtin_amdgcn_exp2f(mrow - mn);
      mrow = mn;
      lrow *= corr;
#pragma unroll
      for (int nt = 0; nt < 4; ++nt)
#pragma unroll
        for (int i = 0; i < 4; ++i) accO[nt][i] *= corr;
    }

    float p[16];
#pragma unroll
    for (int nt = 0; nt < 4; ++nt)
#pragma unroll
      for (int i = 0; i < 4; ++i)
        p[nt * 4 + i] = __builtin_amdgcn_exp2f(accS[nt][i] - mrow);
    const float s0 = (p[0] + p[1]) + (p[2] + p[3]);
    const float s1 = (p[4] + p[5]) + (p[6] + p[7]);
    const float s2 = (p[8] + p[9]) + (p[10] + p[11]);
    const float s3 = (p[12] + p[13]) + (p[14] + p[15]);
    float rs = (s0 + s1) + (s2 + s3);
    rs += __shfl_xor(rs, 16);
    rs += __shfl_xor(rs, 32);
    lrow += rs;

    // pack P^T rows (kv ascending) into dwords: pk[nt][d] = (i=2d, i=2d+1)
    uint32_t pk[4][2];
#pragma unroll
    for (int nt = 0; nt < 4; ++nt)
#pragma unroll
      for (int d = 0; d < 2; ++d)
        pk[nt][d] = (uint32_t)b2u(p[nt * 4 + 2 * d]) |
                    ((uint32_t)b2u(p[nt * 4 + 2 * d + 1]) << 16);

    // PV^T: B-frag dword w <- src lane ((g&1)*2+(w>>1))*16+cl, reg nt=2ks+(g>>1)
    const __bf16* sVb = sV[buf];
#pragma unroll
    for (int ks = 0; ks < 2; ++ks) {
      const int n0i = ks * 2, n1i = n0i + 1;
      union { uint32_t u[4]; bf16x8 v; } bP;
      {
        const int t0 = __builtin_amdgcn_ds_bpermute(aA, (int)pk[n0i][0]);
        const int t1 = __builtin_amdgcn_ds_bpermute(aA, (int)pk[n1i][0]);
        bP.u[0] = (uint32_t)(ghi ? t1 : t0);
        const int t2 = __builtin_amdgcn_ds_bpermute(aA, (int)pk[n0i][1]);
        const int t3 = __builtin_amdgcn_ds_bpermute(aA, (int)pk[n1i][1]);
        bP.u[1] = (uint32_t)(ghi ? t3 : t2);
        const int t4 = __builtin_amdgcn_ds_bpermute(aB, (int)pk[n0i][0]);
        const int t5 = __builtin_amdgcn_ds_bpermute(aB, (int)pk[n1i][0]);
        bP.u[2] = (uint32_t)(ghi ? t5 : t4);
        const int t6 = __builtin_amdgcn_ds_bpermute(aB, (int)pk[n0i][1]);
        const int t7 = __builtin_amdgcn_ds_bpermute(aB, (int)pk[n1i][1]);
        bP.u[3] = (uint32_t)(ghi ? t7 : t6);
      }
      const int chunk = (ks * 4 + g) ^ (cl & 7);
      __builtin_amdgcn_s_setprio(1);
#pragma unroll
      for (int nt = 0; nt < 4; ++nt) {
        const int e = nt * 16 + cl;
        bf16x8 bv = *reinterpret_cast<const bf16x8*>(sVb + e * 64 + chunk * 8);
        accO[nt] = __builtin_amdgcn_mfma_f32_16x16x32_bf16(bv, bP.v, accO[nt], 0, 0, 0);
      }
      __builtin_amdgcn_s_setprio(0);
    }

    __syncthreads();  // drains K/V DMA; all waves done with buf
    buf ^= 1;
  }

  // epilogue: accO^T holds [e = nt*16+g*4+i][q = cl]; 8B packed stores
  const float inv = 1.0f / lrow;
  const int qrow = q0 + wid * 16 + cl;
  hbf* arow = attn + ((size_t)(bh >> 4) * 4096 + qrow) * 1024 + (bh & 15) * 64;
#pragma unroll
  for (int nt = 0; nt < 4; ++nt) {
    ushort4 o;
    o.x = b2u(accO[nt][0] * inv);
    o.y = b2u(accO[nt][1] * inv);
    o.z = b2u(accO[nt][2] * inv);
    o.w = b2u(accO[nt][3] * inv);
    *reinterpret_cast<ushort4*>(arow + nt * 16 + g * 4) = o;
  }
}

// ---------------- output projection GEMM ----------------

__global__ __launch_bounds__(256) void k_gemm_out(
    const hbf* __restrict__ A, const hbf* __restrict__ Bw,
    const float* __restrict__ bp, float* __restrict__ out) {
  __shared__ __align__(16) hbf sA[128 * 64];
  __shared__ __align__(16) hbf sB[128 * 64];
  const int tid = threadIdx.x;
  const int lane = tid & 63, wid = tid >> 6;
  const int m0 = blockIdx.x * 128, n0 = blockIdx.y * 128;
  const int g = lane >> 4, cl = lane & 15;

  const f32x4 fz = {0.f, 0.f, 0.f, 0.f};
  f32x4 acc[4][4];
#pragma unroll
  for (int a = 0; a < 4; ++a)
#pragma unroll
    for (int b = 0; b < 4; ++b) acc[a][b] = fz;

  const int srow = wid * 32 + (lane >> 3);
  const int scol = (lane & 7) * 8;

  for (int kt = 0; kt < 16; ++kt) {
    const int k0 = kt * 64;
#pragma unroll
    for (int t = 0; t < 4; ++t) {
      const int r = srow + t * 8;
      gload_lds16(A + (size_t)(m0 + r) * 1024 + k0 + scol, sA + (wid * 32 + t * 8) * 64);
      gload_lds16(Bw + (size_t)(n0 + r) * 1024 + k0 + scol, sB + (wid * 32 + t * 8) * 64);
    }
    __syncthreads();
#pragma unroll
    for (int ks = 0; ks < 2; ++ks) {
      const int ko = ks * 32 + g * 8;
      bf16x8 af[4], bfr[4];
#pragma unroll
      for (int rt = 0; rt < 4; ++rt)
        af[rt] = *reinterpret_cast<const bf16x8*>(sA + ((wid & 1) * 64 + rt * 16 + cl) * 64 + ko);
#pragma unroll
      for (int ct = 0; ct < 4; ++ct)
        bfr[ct] = *reinterpret_cast<const bf16x8*>(sB + ((wid >> 1) * 64 + ct * 16 + cl) * 64 + ko);
#pragma unroll
      for (int rt = 0; rt < 4; ++rt)
#pragma unroll
        for (int ct = 0; ct < 4; ++ct)
          acc[rt][ct] = __builtin_amdgcn_mfma_f32_16x16x32_bf16(af[rt], bfr[ct], acc[rt][ct], 0, 0, 0);
    }
    __syncthreads();
  }

#pragma unroll
  for (int rt = 0; rt < 4; ++rt)
#pragma unroll
    for (int ct = 0; ct < 4; ++ct) {
      const int colg = n0 + (wid >> 1) * 64 + ct * 16 + cl;
      const float bi = bp[colg];
#pragma unroll
      for (int i = 0; i < 4; ++i) {
        const int rowg = m0 + (wid & 1) * 64 + rt * 16 + g * 4 + i;
        out[(size_t)rowg * 1024 + colg] = acc[rt][ct][i] + bi;
      }
    }
}

// ---------------- launcher ----------------

extern "C" void kernel_launch(void* const* d_in, const int* in_sizes, int n_in,
                              void* d_out, int out_size, void* d_ws, size_t ws_size,
                              hipStream_t stream) {
  const float* x  = (const float*)d_in[0];
  const float* Wq = (const float*)d_in[1];
  const float* Wk = (const float*)d_in[2];
  const float* Wv = (const float*)d_in[3];
  const float* bq = (const float*)d_in[4];
  const float* bk = (const float*)d_in[5];
  const float* bv = (const float*)d_in[6];
  const float* Wp = (const float*)d_in[7];
  const float* bp = (const float*)d_in[8];
  float* out = (float*)d_out;

  char* ws = (char*)d_ws;
  hbf*   xb    = (hbf*)ws;                                   // 16 MiB (reused as attn_out)
  hbf*   Wt    = (hbf*)(ws + 16777216);                      // 6 MiB
  hbf*   Wpt   = (hbf*)(ws + 16777216 + 6291456);            // 2 MiB
  float* biasc = (float*)(ws + 16777216 + 6291456 + 2097152);// 12 KiB (+pad)
  hbf*   qkv   = (hbf*)(ws + 16777216 + 6291456 + 2097152 + 16384); // 48 MiB
  hbf*   attn  = xb;

  k_cvt_x   <<<8192,  256, 0, stream>>>(x, xb);
  k_cvt_w   <<<12288, 256, 0, stream>>>(Wq, Wk, Wv, Wt);
  k_cvt_bias<<<12,    256, 0, stream>>>(bq, bk, bv, biasc);
  k_cvt_wp  <<<4096,  256, 0, stream>>>(Wp, Wpt);

  dim3 g1(64, 24); k_gemm_qkv<<<g1, 256, 0, stream>>>(xb, Wt, biasc, qkv);
  dim3 g2(32, 64); k_flash   <<<g2, 256, 0, stream>>>(qkv, attn);
  dim3 g3(64, 8);  k_gemm_out<<<g3, 256, 0, stream>>>(attn, Wpt, bp, out);
}

// Round 9
// 251.729 us; speedup vs baseline: 1.2240x; 1.2048x over previous
//
#include <hip/hip_runtime.h>
#include <hip/hip_bf16.h>
#include <stdint.h>

// B=2, T=4096, D=1024, H=16, HS=64. Pipeline:
// cvt -> GEMM qkv (V written TRANSPOSED [bh][e][t], packed stores) -> flash attn
// (32x32 MFMA swapped QK^T, in-register softmax, cvt_pk+permlane32_swap P
// redistribution, defer-rescale, dbuf swizzled K/V via global_load_lds) -> GEMM out.

typedef __bf16 bf16x8 __attribute__((ext_vector_type(8)));
typedef float f32x4 __attribute__((ext_vector_type(4)));
typedef float f32x16 __attribute__((ext_vector_type(16)));
typedef __attribute__((address_space(1))) void gvoid_t;
typedef __attribute__((address_space(3))) void lvoid_t;

using hbf = __hip_bfloat16;

#define QSCALE (0.125f * 1.44269504088896f)  // 1/sqrt(HS) * log2(e)

static __device__ __forceinline__ void gload_lds16(const void* g, void* l) {
  __builtin_amdgcn_global_load_lds((gvoid_t*)g, (lvoid_t*)l, 16, 0, 0);
}

static __device__ __forceinline__ uint16_t b2u(float x) {
  hbf h = __float2bfloat16(x);
  return *reinterpret_cast<uint16_t*>(&h);
}

static __device__ __forceinline__ uint32_t cvtpk(float lo, float hi) {
  uint32_t r;
  asm("v_cvt_pk_bf16_f32 %0, %1, %2" : "=v"(r) : "v"(lo), "v"(hi));
  return r;
}

// v_permlane32_swap_b32 semantics (gfx950): result0 = {op0.lanes[0:31],
// op1.lanes[0:31] moved to 32:63}; result1 = {op0.lanes[32:63] moved to 0:31,
// op1.lanes[32:63]}. In-place on both operands.
static __device__ __forceinline__ void pl32swap(uint32_t& x, uint32_t& y) {
  asm volatile("v_permlane32_swap_b32 %0, %1" : "+v"(x), "+v"(y));
}

// ---------------- converters ----------------

__global__ void k_cvt_x(const float* __restrict__ x, hbf* __restrict__ xb) {
  int i = (blockIdx.x * 256 + threadIdx.x) * 4;
  float4 v = *reinterpret_cast<const float4*>(x + i);
  hbf h[4] = {__float2bfloat16(v.x), __float2bfloat16(v.y),
              __float2bfloat16(v.z), __float2bfloat16(v.w)};
  *reinterpret_cast<ushort4*>(xb + i) = *reinterpret_cast<ushort4*>(h);
}

__global__ void k_cvt_w(const float* __restrict__ Wq, const float* __restrict__ Wk,
                        const float* __restrict__ Wv, hbf* __restrict__ Wt) {
  int idx = blockIdx.x * 256 + threadIdx.x;   // 3072*1024
  int d = idx & 1023, r = idx >> 10;
  int m = r >> 10, rem = r & 1023;
  int h = rem >> 6, e = rem & 63;
  const float* W = (m == 0) ? Wq : (m == 1) ? Wk : Wv;
  float v = W[(h << 10 | d) * 64 + e];
  if (m == 0) v *= QSCALE;
  Wt[idx] = __float2bfloat16(v);
}

__global__ void k_cvt_bias(const float* __restrict__ bq, const float* __restrict__ bk,
                           const float* __restrict__ bv, float* __restrict__ biasc) {
  int r = blockIdx.x * 256 + threadIdx.x;     // 0..3071
  int m = r >> 10, rem = r & 1023;
  const float* bsrc = (m == 0) ? bq : (m == 1) ? bk : bv;
  float v = bsrc[rem];
  if (m == 0) v *= QSCALE;
  biasc[r] = v;
}

__global__ void k_cvt_wp(const float* __restrict__ Wp, hbf* __restrict__ Wpt) {
  int idx = blockIdx.x * 256 + threadIdx.x;   // 1024*1024
  int o = idx >> 10, d = idx & 1023;
  Wpt[idx] = __float2bfloat16(Wp[(d << 10) + o]);
}

// ---------------- QKV projection GEMM ----------------
// Q,K -> qkv[mi][bh][t][e] ; V -> transposed [bh][e][t] (packed 8B stores).

__global__ __launch_bounds__(256) void k_gemm_qkv(
    const hbf* __restrict__ A, const hbf* __restrict__ Bw,
    const float* __restrict__ biasc, hbf* __restrict__ qkv) {
  __shared__ __align__(16) hbf sA[128 * 64];
  __shared__ __align__(16) hbf sB[128 * 64];
  const int tid = threadIdx.x;
  const int lane = tid & 63, wid = tid >> 6;
  const int m0 = blockIdx.x * 128, n0 = blockIdx.y * 128;
  const int g = lane >> 4, cl = lane & 15;

  const f32x4 fz = {0.f, 0.f, 0.f, 0.f};
  f32x4 acc[4][4];
#pragma unroll
  for (int a = 0; a < 4; ++a)
#pragma unroll
    for (int b = 0; b < 4; ++b) acc[a][b] = fz;

  const int srow = wid * 32 + (lane >> 3);
  const int scol = (lane & 7) * 8;

  for (int kt = 0; kt < 16; ++kt) {
    const int k0 = kt * 64;
#pragma unroll
    for (int t = 0; t < 4; ++t) {
      const int r = srow + t * 8;
      gload_lds16(A + (size_t)(m0 + r) * 1024 + k0 + scol, sA + (wid * 32 + t * 8) * 64);
      gload_lds16(Bw + (size_t)(n0 + r) * 1024 + k0 + scol, sB + (wid * 32 + t * 8) * 64);
    }
    __syncthreads();
#pragma unroll
    for (int ks = 0; ks < 2; ++ks) {
      const int ko = ks * 32 + g * 8;
      bf16x8 af[4], bfr[4];
#pragma unroll
      for (int rt = 0; rt < 4; ++rt)
        af[rt] = *reinterpret_cast<const bf16x8*>(sA + ((wid & 1) * 64 + rt * 16 + cl) * 64 + ko);
#pragma unroll
      for (int ct = 0; ct < 4; ++ct)
        bfr[ct] = *reinterpret_cast<const bf16x8*>(sB + ((wid >> 1) * 64 + ct * 16 + cl) * 64 + ko);
#pragma unroll
      for (int rt = 0; rt < 4; ++rt)
#pragma unroll
        for (int ct = 0; ct < 4; ++ct)
          acc[rt][ct] = __builtin_amdgcn_mfma_f32_16x16x32_bf16(af[rt], bfr[ct], acc[rt][ct], 0, 0, 0);
    }
    __syncthreads();
  }

#pragma unroll
  for (int rt = 0; rt < 4; ++rt)
#pragma unroll
    for (int ct = 0; ct < 4; ++ct) {
      const int colg = n0 + (wid >> 1) * 64 + ct * 16 + cl;
      const int mi = colg >> 10, rem = colg & 1023;
      const int h = rem >> 6, e = rem & 63;
      const float bi = biasc[colg];
      if (mi == 2) {
        // V transposed: 4 consecutive-t values -> one 8B store
        const int t0 = m0 + (wid & 1) * 64 + rt * 16 + g * 4;
        const int b = t0 >> 12, t = t0 & 4095;
        ushort4 o;
        o.x = b2u(acc[rt][ct][0] + bi);
        o.y = b2u(acc[rt][ct][1] + bi);
        o.z = b2u(acc[rt][ct][2] + bi);
        o.w = b2u(acc[rt][ct][3] + bi);
        *reinterpret_cast<ushort4*>(
            qkv + (size_t)64 * 262144 + (size_t)(b * 16 + h) * 262144 + (size_t)e * 4096 + t) = o;
      } else {
#pragma unroll
        for (int i = 0; i < 4; ++i) {
          const int rowg = m0 + (wid & 1) * 64 + rt * 16 + g * 4 + i;
          const int b = rowg >> 12, t = rowg & 4095;
          qkv[(((size_t)mi * 32 + b * 16 + h) * 4096 + t) * 64 + e] =
              __float2bfloat16(acc[rt][ct][i] + bi);
        }
      }
    }
}

// ---------------- flash attention ----------------
// grid (bh=32, 32); qtb = 31 - blockIdx.y. Q-tile 128: 4 waves x 32 q-rows.
// 32x32x16 MFMA, swapped: accS[t] = mfma(K, Q) = S^T[kv][q]; lane l owns
// q-col l&31, kv rows (i&3)+8*(i>>2)+4*(l>>5)+32t. Row stats: in-reg tree +
// shfl_xor(32). Defer-rescale (THR=8, exp2). P->bf16 via v_cvt_pk_bf16_f32,
// redistributed to PV B-frag via v_permlane32_swap_b32 (VALU, no DS).
// PV = mfma(V^T, P^T) -> O^T[e][q]. K and V^T staged via XOR-swizzled
// global_load_lds (V pre-transposed by GEMM1). Dbuf, one barrier/iter.

__global__ __launch_bounds__(256) void k_flash(
    const hbf* __restrict__ qkv, hbf* __restrict__ attn) {
  __shared__ __align__(16) __bf16 sK[2][64 * 64];
  __shared__ __align__(16) __bf16 sV[2][64 * 64];
  const int tid = threadIdx.x, lane = tid & 63, wq = tid >> 6;
  const int h = lane >> 5, r31 = lane & 31;
  const int bh = blockIdx.x;
  const int qtb = (int)gridDim.y - 1 - (int)blockIdx.y;  // 0..31
  const int q0 = qtb * 128;
  const int ntile = 2 * qtb + 2;
  const hbf* Q  = qkv + (size_t)bh * 262144;
  const hbf* Kp = qkv + (size_t)(32 + bh) * 262144;
  const hbf* Vp = qkv + (size_t)(64 + bh) * 262144;  // [e=64][t=4096]
  const float NEG_INF = -__builtin_inff();

  const int koff = (wq * 16 + (lane >> 3)) * 64 + (((lane & 7) ^ (lane >> 3)) * 8);
  const int voff = (wq * 16 + (lane >> 3)) * 4096 + (((lane & 7) ^ (lane >> 3)) * 8);

  // Q-frag (B operand): lane l holds Q[q=q0+wq*32+r31][e = ks*16 + h*8 .. +8]
  const int qrow = q0 + wq * 32 + r31;
  bf16x8 aq[4];
#pragma unroll
  for (int ks = 0; ks < 4; ++ks)
    aq[ks] = *reinterpret_cast<const bf16x8*>(Q + (size_t)qrow * 64 + ks * 16 + h * 8);

  f32x16 accO[2];
#pragma unroll
  for (int et = 0; et < 2; ++et)
#pragma unroll
    for (int i = 0; i < 16; ++i) accO[et][i] = 0.f;
  float mrow = NEG_INF, lrow = 0.f;  // lane owns q-row r31's stats

  // prologue: stage tile 0 into buf 0
  gload_lds16(Kp + koff,         &sK[0][wq * 1024]);
  gload_lds16(Kp + koff + 512,   &sK[0][wq * 1024 + 512]);
  gload_lds16(Vp + voff,         &sV[0][wq * 1024]);
  gload_lds16(Vp + voff + 32768, &sV[0][wq * 1024 + 512]);
  __syncthreads();

  const int qmaxw = q0 + wq * 32 + 31;
  int buf = 0;
  for (int jt = 0; jt < ntile; ++jt) {
    if (jt < ntile - 1) {  // prefetch next tile (pure DMA)
      const hbf* Kg = Kp + (size_t)(jt + 1) * 4096;
      gload_lds16(Kg + koff,       &sK[buf ^ 1][wq * 1024]);
      gload_lds16(Kg + koff + 512, &sK[buf ^ 1][wq * 1024 + 512]);
      const hbf* Vg = Vp + (jt + 1) * 64;
      gload_lds16(Vg + voff,         &sV[buf ^ 1][wq * 1024]);
      gload_lds16(Vg + voff + 32768, &sV[buf ^ 1][wq * 1024 + 512]);
    }

    if (64 * jt <= qmaxw) {  // wave has unmasked work in this tile
      const __bf16* sKb = sK[buf];
      const __bf16* sVb = sV[buf];

      // S^T = K Q^T : two 32kv x 32q tiles
      f32x16 accS[2];
      __builtin_amdgcn_s_setprio(1);
#pragma unroll
      for (int t = 0; t < 2; ++t) {
        f32x16 s;
#pragma unroll
        for (int i = 0; i < 16; ++i) s[i] = 0.f;
#pragma unroll
        for (int ks = 0; ks < 4; ++ks) {
          bf16x8 ak = *reinterpret_cast<const bf16x8*>(
              sKb + (t * 32 + r31) * 64 + (((2 * ks + h) ^ (r31 & 7)) * 8));
          s = __builtin_amdgcn_mfma_f32_32x32x16_bf16(ak, aq[ks], s, 0, 0, 0);
        }
        accS[t] = s;
      }
      __builtin_amdgcn_s_setprio(0);

      if (64 * jt + 63 > q0 + wq * 32) {  // diagonal region: mask kv > q
#pragma unroll
        for (int t = 0; t < 2; ++t)
#pragma unroll
          for (int i = 0; i < 16; ++i) {
            const int kvg = 64 * jt + 32 * t + (i & 3) + 8 * (i >> 2) + 4 * h;
            if (kvg > qrow) accS[t][i] = NEG_INF;
          }
      }

      // row stats: pairwise tree over own 32 + one cross-half exchange
      float a0 = fmaxf(fmaxf(accS[0][0], accS[0][1]), fmaxf(accS[0][2], accS[0][3]));
      float a1 = fmaxf(fmaxf(accS[0][4], accS[0][5]), fmaxf(accS[0][6], accS[0][7]));
      float a2 = fmaxf(fmaxf(accS[0][8], accS[0][9]), fmaxf(accS[0][10], accS[0][11]));
      float a3 = fmaxf(fmaxf(accS[0][12], accS[0][13]), fmaxf(accS[0][14], accS[0][15]));
      float a4 = fmaxf(fmaxf(accS[1][0], accS[1][1]), fmaxf(accS[1][2], accS[1][3]));
      float a5 = fmaxf(fmaxf(accS[1][4], accS[1][5]), fmaxf(accS[1][6], accS[1][7]));
      float a6 = fmaxf(fmaxf(accS[1][8], accS[1][9]), fmaxf(accS[1][10], accS[1][11]));
      float a7 = fmaxf(fmaxf(accS[1][12], accS[1][13]), fmaxf(accS[1][14], accS[1][15]));
      float pmax = fmaxf(fmaxf(fmaxf(a0, a1), fmaxf(a2, a3)),
                         fmaxf(fmaxf(a4, a5), fmaxf(a6, a7)));
      pmax = fmaxf(pmax, __shfl_xor(pmax, 32));

      if (!__all(pmax - mrow <= 8.f)) {  // defer-rescale (T13)
        const float mn = fmaxf(mrow, pmax);
        const float corr = __builtin_amdgcn_exp2f(mrow - mn);
        mrow = mn;
        lrow *= corr;
#pragma unroll
        for (int et = 0; et < 2; ++et)
#pragma unroll
          for (int i = 0; i < 16; ++i) accO[et][i] *= corr;
      }

      // p = exp2(S - m) in place; row-sum
#pragma unroll
      for (int t = 0; t < 2; ++t)
#pragma unroll
        for (int i = 0; i < 16; ++i)
          accS[t][i] = __builtin_amdgcn_exp2f(accS[t][i] - mrow);
      float s0 = (accS[0][0] + accS[0][1]) + (accS[0][2] + accS[0][3]);
      float s1 = (accS[0][4] + accS[0][5]) + (accS[0][6] + accS[0][7]);
      float s2 = (accS[0][8] + accS[0][9]) + (accS[0][10] + accS[0][11]);
      float s3 = (accS[0][12] + accS[0][13]) + (accS[0][14] + accS[0][15]);
      float s4 = (accS[1][0] + accS[1][1]) + (accS[1][2] + accS[1][3]);
      float s5 = (accS[1][4] + accS[1][5]) + (accS[1][6] + accS[1][7]);
      float s6 = (accS[1][8] + accS[1][9]) + (accS[1][10] + accS[1][11]);
      float s7 = (accS[1][12] + accS[1][13]) + (accS[1][14] + accS[1][15]);
      float rs = ((s0 + s1) + (s2 + s3)) + ((s4 + s5) + (s6 + s7));
      rs += __shfl_xor(rs, 32);
      lrow += rs;

      // pack to bf16 dwords: d0/d1[t][r4] ; r4 = i>>2 covers kv (i&3) pairs
      uint32_t d0[2][4], d1[2][4];
#pragma unroll
      for (int t = 0; t < 2; ++t)
#pragma unroll
        for (int r4 = 0; r4 < 4; ++r4) {
          d0[t][r4] = cvtpk(accS[t][4 * r4 + 0], accS[t][4 * r4 + 1]);
          d1[t][r4] = cvtpk(accS[t][4 * r4 + 2], accS[t][4 * r4 + 3]);
        }

      // PV: per k-slice kb, assemble P^T B-frag via 2 permlane32_swap.
      // u[0] needs {h=0: own d0[ra]; h=1: partner d0[rb]} = newX of swap(d0[ra], d0[rb]);
      // u[2] needs {h=0: partner d0[ra]; h=1: own d0[rb]} = newY. Same for d1 -> u[1],u[3].
#pragma unroll
      for (int kb = 0; kb < 4; ++kb) {
        const int t = kb >> 1, ra = 2 * (kb & 1), rb = ra + 1;
        uint32_t x0 = d0[t][ra], y0 = d0[t][rb];
        uint32_t x1 = d1[t][ra], y1 = d1[t][rb];
        pl32swap(x0, y0);
        pl32swap(x1, y1);
        union { uint32_t u[4]; bf16x8 v; } bP;
        bP.u[0] = x0; bP.u[1] = x1; bP.u[2] = y0; bP.u[3] = y1;
        __builtin_amdgcn_s_setprio(1);
#pragma unroll
        for (int et = 0; et < 2; ++et) {
          bf16x8 av = *reinterpret_cast<const bf16x8*>(
              sVb + (et * 32 + r31) * 64 + (((2 * kb + h) ^ (r31 & 7)) * 8));
          accO[et] = __builtin_amdgcn_mfma_f32_32x32x16_bf16(av, bP.v, accO[et], 0, 0, 0);
        }
        __builtin_amdgcn_s_setprio(0);
      }
    }

    __syncthreads();  // drains K/V DMA; all waves done with buf
    buf ^= 1;
  }

  // epilogue: accO[et][i] = O^T[e = (i&3)+8*(i>>2)+4h+32et][q = r31]
  const float inv = 1.0f / lrow;
  hbf* arow = attn + ((size_t)(bh >> 4) * 4096 + qrow) * 1024 + (bh & 15) * 64;
#pragma unroll
  for (int et = 0; et < 2; ++et)
#pragma unroll
    for (int r4 = 0; r4 < 4; ++r4) {
      const int e0 = et * 32 + 8 * r4 + 4 * h;
      ushort4 o;
      o.x = b2u(accO[et][4 * r4 + 0] * inv);
      o.y = b2u(accO[et][4 * r4 + 1] * inv);
      o.z = b2u(accO[et][4 * r4 + 2] * inv);
      o.w = b2u(accO[et][4 * r4 + 3] * inv);
      *reinterpret_cast<ushort4*>(arow + e0) = o;
    }
}

// ---------------- output projection GEMM ----------------

__global__ __launch_bounds__(256) void k_gemm_out(
    const hbf* __restrict__ A, const hbf* __restrict__ Bw,
    const float* __restrict__ bp, float* __restrict__ out) {
  __shared__ __align__(16) hbf sA[128 * 64];
  __shared__ __align__(16) hbf sB[128 * 64];
  const int tid = threadIdx.x;
  const int lane = tid & 63, wid = tid >> 6;
  const int m0 = blockIdx.x * 128, n0 = blockIdx.y * 128;
  const int g = lane >> 4, cl = lane & 15;

  const f32x4 fz = {0.f, 0.f, 0.f, 0.f};
  f32x4 acc[4][4];
#pragma unroll
  for (int a = 0; a < 4; ++a)
#pragma unroll
    for (int b = 0; b < 4; ++b) acc[a][b] = fz;

  const int srow = wid * 32 + (lane >> 3);
  const int scol = (lane & 7) * 8;

  for (int kt = 0; kt < 16; ++kt) {
    const int k0 = kt * 64;
#pragma unroll
    for (int t = 0; t < 4; ++t) {
      const int r = srow + t * 8;
      gload_lds16(A + (size_t)(m0 + r) * 1024 + k0 + scol, sA + (wid * 32 + t * 8) * 64);
      gload_lds16(Bw + (size_t)(n0 + r) * 1024 + k0 + scol, sB + (wid * 32 + t * 8) * 64);
    }
    __syncthreads();
#pragma unroll
    for (int ks = 0; ks < 2; ++ks) {
      const int ko = ks * 32 + g * 8;
      bf16x8 af[4], bfr[4];
#pragma unroll
      for (int rt = 0; rt < 4; ++rt)
        af[rt] = *reinterpret_cast<const bf16x8*>(sA + ((wid & 1) * 64 + rt * 16 + cl) * 64 + ko);
#pragma unroll
      for (int ct = 0; ct < 4; ++ct)
        bfr[ct] = *reinterpret_cast<const bf16x8*>(sB + ((wid >> 1) * 64 + ct * 16 + cl) * 64 + ko);
#pragma unroll
      for (int rt = 0; rt < 4; ++rt)
#pragma unroll
        for (int ct = 0; ct < 4; ++ct)
          acc[rt][ct] = __builtin_amdgcn_mfma_f32_16x16x32_bf16(af[rt], bfr[ct], acc[rt][ct], 0, 0, 0);
    }
    __syncthreads();
  }

#pragma unroll
  for (int rt = 0; rt < 4; ++rt)
#pragma unroll
    for (int ct = 0; ct < 4; ++ct) {
      const int colg = n0 + (wid >> 1) * 64 + ct * 16 + cl;
      const float bi = bp[colg];
#pragma unroll
      for (int i = 0; i < 4; ++i) {
        const int rowg = m0 + (wid & 1) * 64 + rt * 16 + g * 4 + i;
        out[(size_t)rowg * 1024 + colg] = acc[rt][ct][i] + bi;
      }
    }
}

// ---------------- launcher ----------------

extern "C" void kernel_launch(void* const* d_in, const int* in_sizes, int n_in,
                              void* d_out, int out_size, void* d_ws, size_t ws_size,
                              hipStream_t stream) {
  const float* x  = (const float*)d_in[0];
  const float* Wq = (const float*)d_in[1];
  const float* Wk = (const float*)d_in[2];
  const float* Wv = (const float*)d_in[3];
  const float* bq = (const float*)d_in[4];
  const float* bk = (const float*)d_in[5];
  const float* bv = (const float*)d_in[6];
  const float* Wp = (const float*)d_in[7];
  const float* bp = (const float*)d_in[8];
  float* out = (float*)d_out;

  char* ws = (char*)d_ws;
  hbf*   xb    = (hbf*)ws;                                   // 16 MiB (reused as attn_out)
  hbf*   Wt    = (hbf*)(ws + 16777216);                      // 6 MiB
  hbf*   Wpt   = (hbf*)(ws + 16777216 + 6291456);            // 2 MiB
  float* biasc = (float*)(ws + 16777216 + 6291456 + 2097152);// 12 KiB (+pad)
  hbf*   qkv   = (hbf*)(ws + 16777216 + 6291456 + 2097152 + 16384); // 48 MiB
  hbf*   attn  = xb;

  k_cvt_x   <<<8192,  256, 0, stream>>>(x, xb);
  k_cvt_w   <<<12288, 256, 0, stream>>>(Wq, Wk, Wv, Wt);
  k_cvt_bias<<<12,    256, 0, stream>>>(bq, bk, bv, biasc);
  k_cvt_wp  <<<4096,  256, 0, stream>>>(Wp, Wpt);

  dim3 g1(64, 24); k_gemm_qkv<<<g1, 256, 0, stream>>>(xb, Wt, biasc, qkv);
  dim3 g2(32, 32); k_flash   <<<g2, 256, 0, stream>>>(qkv, attn);
  dim3 g3(64, 8);  k_gemm_out<<<g3, 256, 0, stream>>>(attn, Wpt, bp, out);
}